// Round 2
// 1434.325 us; speedup vs baseline: 1.4634x; 1.4634x over previous
//
#include <hip/hip_runtime.h>
#include <math.h>

// CovNet: P = L L^T + Q where L = tril-net(MLP(log diag(P_prev)))
// Round 2 (resubmit — prior bench died to container infra, no signal):
//   covnet_mlp: pad s_h1/s_h2 leading dim to 257 (kills 8-way conflict on h
//               broadcasts and 32-way conflict in the tail), pad s_ld to 33,
//               unroll K-loops x4 for 4-deep W-row prefetch.
//   covnet_llt: REWRITE. Old version punned float arrays through float4 casts
//               -> SROA defeated -> r0/r1/p0/p1 in scratch (VGPR_Count=128,
//               ~2.3 GB excess HBM traffic). New version: native float4 row
//               registers, accumulators chunked 4x8 so per-thread state fits
//               ~110 VGPRs, chunk results stored straight to global (L2
//               merges the scattered 16B stores into full lines).

#define NXD   32
#define HID   256
#define NOUTC 528
#define TBA   32          // batch tile, kernel A
#define TBB   8           // batch tile, kernel B
#define LSTR  36          // L row stride (16B-aligned rows for b128 reads)
#define SLAB  (NXD * LSTR + 4)   // 1156: +4 words rotates banks across b-slabs
#define HSTR  (HID + 1)   // 257: conflict-free h broadcasts (bank = (b+k)%32)
#define DSTR  (NXD + 1)   // 33:  conflict-free log-diag broadcasts

__device__ __forceinline__ void fma4(float4& a, const float s, const float4& w) {
  a.x = fmaf(s, w.x, a.x); a.y = fmaf(s, w.y, a.y);
  a.z = fmaf(s, w.z, a.z); a.w = fmaf(s, w.w, a.w);
}
__device__ __forceinline__ float4 ld4(const float* p) {
  return *(const float4*)p;
}
__device__ __forceinline__ float4 tanh4(float4 a, const float4 b) {
  return make_float4(tanhf(a.x + b.x), tanhf(a.y + b.y),
                     tanhf(a.z + b.z), tanhf(a.w + b.w));
}
// scalar stores: rows of stride-257 LDS are not 16B-aligned
__device__ __forceinline__ void st4s(float* p, const float4 v) {
  p[0] = v.x; p[1] = v.y; p[2] = v.z; p[3] = v.w;
}

__global__ __launch_bounds__(256, 2)
void covnet_mlp(const float* __restrict__ Pp,
                const float* __restrict__ W1, const float* __restrict__ B1,
                const float* __restrict__ W2, const float* __restrict__ B2,
                const float* __restrict__ W3, const float* __restrict__ B3,
                float* __restrict__ outg) {
  __shared__ float s_ld[TBA][DSTR];    // ~4 KB
  __shared__ float s_h1[TBA][HSTR];    // ~32 KB
  __shared__ float s_h2[TBA][HSTR];    // ~32 KB  -> ~70 KB total, 2 blocks/CU
  const int tid = threadIdx.x;
  const int jt  = tid & 31;           // j-column group (strided ownership)
  const int bt  = tid >> 5;           // 0..7
  const int b0  = bt << 2;            // 4 batch rows per thread
  const long base_b = (long)blockIdx.x * TBA;

  // ---- phase 0: log of clipped diagonal ----
  for (int idx = tid; idx < TBA * NXD; idx += 256) {
    const int b = idx >> 5, i = idx & 31;
    const float v = Pp[(base_b + b) * (NXD * NXD) + i * (NXD + 1)];
    s_ld[b][i] = __logf(fmaxf(v, 1e-6f));
  }
  __syncthreads();

  // ---- phase 1: h1 = tanh(ld @ W1 + b1), K=32, N=256 ----
  {
    float4 acc[4][2];
#pragma unroll
    for (int bb = 0; bb < 4; ++bb) {
      acc[bb][0] = make_float4(0.f, 0.f, 0.f, 0.f);
      acc[bb][1] = make_float4(0.f, 0.f, 0.f, 0.f);
    }
#pragma unroll 4
    for (int k = 0; k < NXD; ++k) {
      const float* wrow = W1 + k * HID + 4 * jt;
      const float4 w0 = ld4(wrow);
      const float4 w1 = ld4(wrow + 128);
      float h[4];
#pragma unroll
      for (int bb = 0; bb < 4; ++bb) h[bb] = s_ld[b0 + bb][k];
#pragma unroll
      for (int bb = 0; bb < 4; ++bb) {
        fma4(acc[bb][0], h[bb], w0);
        fma4(acc[bb][1], h[bb], w1);
      }
    }
    const float4 bv0 = ld4(B1 + 4 * jt);
    const float4 bv1 = ld4(B1 + 4 * jt + 128);
#pragma unroll
    for (int bb = 0; bb < 4; ++bb) {
      st4s(&s_h1[b0 + bb][4 * jt],       tanh4(acc[bb][0], bv0));
      st4s(&s_h1[b0 + bb][4 * jt + 128], tanh4(acc[bb][1], bv1));
    }
  }
  __syncthreads();

  // ---- phase 2: h2 = tanh(h1 @ W2 + b2), K=256, N=256 ----
  {
    float4 acc[4][2];
#pragma unroll
    for (int bb = 0; bb < 4; ++bb) {
      acc[bb][0] = make_float4(0.f, 0.f, 0.f, 0.f);
      acc[bb][1] = make_float4(0.f, 0.f, 0.f, 0.f);
    }
#pragma unroll 4
    for (int k = 0; k < HID; ++k) {
      const float* wrow = W2 + k * HID + 4 * jt;
      const float4 w0 = ld4(wrow);
      const float4 w1 = ld4(wrow + 128);
      float h[4];
#pragma unroll
      for (int bb = 0; bb < 4; ++bb) h[bb] = s_h1[b0 + bb][k];
#pragma unroll
      for (int bb = 0; bb < 4; ++bb) {
        fma4(acc[bb][0], h[bb], w0);
        fma4(acc[bb][1], h[bb], w1);
      }
    }
    const float4 bv0 = ld4(B2 + 4 * jt);
    const float4 bv1 = ld4(B2 + 4 * jt + 128);
#pragma unroll
    for (int bb = 0; bb < 4; ++bb) {
      st4s(&s_h2[b0 + bb][4 * jt],       tanh4(acc[bb][0], bv0));
      st4s(&s_h2[b0 + bb][4 * jt + 128], tanh4(acc[bb][1], bv1));
    }
  }
  __syncthreads();

  // ---- phase 3 main: out[:, 0:512] = h2 @ W3 + b3 ----
  {
    float4 acc[4][4];
#pragma unroll
    for (int bb = 0; bb < 4; ++bb)
#pragma unroll
      for (int jj = 0; jj < 4; ++jj) acc[bb][jj] = make_float4(0.f, 0.f, 0.f, 0.f);
#pragma unroll 4
    for (int k = 0; k < HID; ++k) {
      const float* wrow = W3 + k * NOUTC + 4 * jt;
      float4 w[4];
#pragma unroll
      for (int jj = 0; jj < 4; ++jj) w[jj] = ld4(wrow + 128 * jj);
      float h[4];
#pragma unroll
      for (int bb = 0; bb < 4; ++bb) h[bb] = s_h2[b0 + bb][k];
#pragma unroll
      for (int bb = 0; bb < 4; ++bb)
#pragma unroll
        for (int jj = 0; jj < 4; ++jj) fma4(acc[bb][jj], h[bb], w[jj]);
    }
#pragma unroll
    for (int jj = 0; jj < 4; ++jj) {
      const float4 bv = ld4(B3 + 4 * jt + 128 * jj);
#pragma unroll
      for (int bb = 0; bb < 4; ++bb) {
        float4 r = acc[bb][jj];
        r.x += bv.x; r.y += bv.y; r.z += bv.z; r.w += bv.w;
        *(float4*)&outg[(base_b + b0 + bb) * 1024 + 4 * jt + 128 * jj] = r;
      }
    }
  }

  // ---- phase 3 tail: out[:, 512:528] ----
  {
    const int col = 512 + (tid & 15);
    const int bq  = tid >> 4;          // 0..15, each covers 2 batch rows
    const int bA  = bq * 2, bB = bq * 2 + 1;
    float a0 = 0.f, a1 = 0.f;
#pragma unroll 4
    for (int k = 0; k < HID; ++k) {
      const float w = W3[k * NOUTC + col];
      a0 = fmaf(s_h2[bA][k], w, a0);
      a1 = fmaf(s_h2[bB][k], w, a1);
    }
    const float bv = B3[col];
    outg[(base_b + bA) * 1024 + col] = a0 + bv;
    outg[(base_b + bB) * 1024 + col] = a1 + bv;
  }
}

__global__ __launch_bounds__(128, 2)
void covnet_llt(float* io, const float* __restrict__ Q) {
  __shared__ float s_L[TBB * SLAB];   // 36992 B -> 4 blocks/CU
  const int tid = threadIdx.x;
  const long base_b = (long)blockIdx.x * TBB;

  // ---- build L from raw MLP outputs (read straight from global) ----
  for (int idx = tid; idx < TBB * 1024; idx += 128) {
    const int b = idx >> 10, rc = idx & 1023, r = rc >> 5, c = rc & 31;
    const float* ob = io + (base_b + b) * 1024;
    float v = 0.f;
    if (c < r) {                               // strict lower: 0.1*tanh
      v = 0.1f * tanhf(ob[32 + ((r * (r - 1)) >> 1) + c]);
    } else if (c == r) {                       // diag: clip(softplus+0.01)
      const float x  = ob[r];
      const float sp = (x > 20.f) ? x : log1pf(__expf(x));
      v = fminf(fmaxf(sp + 0.01f, 0.01f), 100.f);
    }
    s_L[b * SLAB + r * LSTR + c] = v;
  }
  __syncthreads();

  // ---- P[i][k] = dot(L row i, L row k); thread owns rows il, il+16 ----
  // Own rows live in native float4 registers (no reinterpret-punning of
  // locals -> SROA keeps them in VGPRs). Output columns computed in 4
  // chunks of 8 so accumulators stay at 16 floats; each chunk is stored
  // straight to global (addresses already consumed pre-barrier).
  const int b  = tid >> 4;   // 0..7
  const int il = tid & 15;
  const int i0 = il, i1 = il + 16;
  const float* Lb = &s_L[b * SLAB];

  float4 r0[8], r1[8];
#pragma unroll
  for (int c4 = 0; c4 < 8; ++c4) {
    r0[c4] = ld4(&Lb[i0 * LSTR + c4 * 4]);
    r1[c4] = ld4(&Lb[i1 * LSTR + c4 * 4]);
  }

  float* out0 = io + (base_b + b) * 1024 + i0 * NXD;
  float* out1 = io + (base_b + b) * 1024 + i1 * NXD;
  const float* q0 = Q + i0 * NXD;
  const float* q1 = Q + i1 * NXD;

#pragma unroll
  for (int kc = 0; kc < 4; ++kc) {
    float p0[8], p1[8];
#pragma unroll
    for (int kk = 0; kk < 8; ++kk) { p0[kk] = 0.f; p1[kk] = 0.f; }
#pragma unroll
    for (int kk = 0; kk < 8; ++kk) {
      const float* lk = &Lb[(kc * 8 + kk) * LSTR];   // row-k broadcast
#pragma unroll
      for (int c4 = 0; c4 < 8; ++c4) {
        const float4 w = ld4(&lk[c4 * 4]);
        p0[kk] = fmaf(r0[c4].x, w.x, p0[kk]);
        p0[kk] = fmaf(r0[c4].y, w.y, p0[kk]);
        p0[kk] = fmaf(r0[c4].z, w.z, p0[kk]);
        p0[kk] = fmaf(r0[c4].w, w.w, p0[kk]);
        p1[kk] = fmaf(r1[c4].x, w.x, p1[kk]);
        p1[kk] = fmaf(r1[c4].y, w.y, p1[kk]);
        p1[kk] = fmaf(r1[c4].z, w.z, p1[kk]);
        p1[kk] = fmaf(r1[c4].w, w.w, p1[kk]);
      }
    }
    const float4 qa0 = ld4(&q0[kc * 8]), qb0 = ld4(&q0[kc * 8 + 4]);
    const float4 qa1 = ld4(&q1[kc * 8]), qb1 = ld4(&q1[kc * 8 + 4]);
    *(float4*)&out0[kc * 8] =
        make_float4(p0[0] + qa0.x, p0[1] + qa0.y, p0[2] + qa0.z, p0[3] + qa0.w);
    *(float4*)&out0[kc * 8 + 4] =
        make_float4(p0[4] + qb0.x, p0[5] + qb0.y, p0[6] + qb0.z, p0[7] + qb0.w);
    *(float4*)&out1[kc * 8] =
        make_float4(p1[0] + qa1.x, p1[1] + qa1.y, p1[2] + qa1.z, p1[3] + qa1.w);
    *(float4*)&out1[kc * 8 + 4] =
        make_float4(p1[4] + qb1.x, p1[5] + qb1.y, p1[6] + qb1.z, p1[7] + qb1.w);
  }
}

extern "C" void kernel_launch(void* const* d_in, const int* in_sizes, int n_in,
                              void* d_out, int out_size, void* d_ws, size_t ws_size,
                              hipStream_t stream) {
  (void)n_in; (void)out_size; (void)d_ws; (void)ws_size;
  const float* Pp = (const float*)d_in[0];
  const float* W1 = (const float*)d_in[1];
  const float* B1 = (const float*)d_in[2];
  const float* W2 = (const float*)d_in[3];
  const float* B2 = (const float*)d_in[4];
  const float* W3 = (const float*)d_in[5];
  const float* B3 = (const float*)d_in[6];
  const float* Q  = (const float*)d_in[7];
  float* out = (float*)d_out;
  const int nb = in_sizes[0] / (NXD * NXD);   // 65536
  covnet_mlp<<<dim3(nb / TBA), dim3(256), 0, stream>>>(Pp, W1, B1, W2, B2, W3, B3, out);
  covnet_llt<<<dim3(nb / TBB), dim3(128), 0, stream>>>(out, Q);
}

// Round 3
// 1011.620 us; speedup vs baseline: 2.0749x; 1.4178x over previous
//
#include <hip/hip_runtime.h>
#include <math.h>

// CovNet: P = L L^T + Q where L = tril-net(MLP(log diag(P_prev)))
// Round 3:
//   covnet_mlp: jt spans 64 column-groups (was 32) -> W-row load redundancy
//               8x -> 4x (L1 pipe was co-critical). h read from LDS as float4
//               per 4-k slice (stride-260 rows, 16B aligned). Fast tanh.
//   covnet_llt: build phase rewritten: zero-init / coalesced lower-tri loop
//               (enumerate tril index t, row via exact fp32 sqrt) / tiny diag
//               loop. No divergent double-pay, no libm tanhf (40+ instr ->
//               ~8 via __expf + __fdividef). Dot/store phases unchanged.

#define NXD   32
#define HID   256
#define NOUTC 528
#define TBA   32          // batch tile, kernel A
#define TBB   8           // batch tile, kernel B
#define LSTR  36          // L row stride (16B-aligned rows for b128 reads)
#define SLAB  (NXD * LSTR + 4)   // 1156: +4 words rotates banks across b-slabs
#define HSTR  260         // h row stride: %4==0 keeps float4 slices aligned
#define DSTR  36          // log-diag row stride, %4==0 for float4 slices
#define NLOW  496         // strict lower-tri count

__device__ __forceinline__ void fma4(float4& a, const float s, const float4& w) {
  a.x = fmaf(s, w.x, a.x); a.y = fmaf(s, w.y, a.y);
  a.z = fmaf(s, w.z, a.z); a.w = fmaf(s, w.w, a.w);
}
__device__ __forceinline__ float4 ld4(const float* p) {
  return *(const float4*)p;
}
// fast tanh: ~8 instr vs ~40 for libm tanhf; |err| ~1e-6, budget is 3.9e-3
__device__ __forceinline__ float ftanh(float x) {
  x = fminf(fmaxf(x, -15.f), 15.f);
  const float e = __expf(2.f * x);
  return __fdividef(e - 1.f, e + 1.f);
}
__device__ __forceinline__ float4 ftanh4(float4 a, const float4 b) {
  return make_float4(ftanh(a.x + b.x), ftanh(a.y + b.y),
                     ftanh(a.z + b.z), ftanh(a.w + b.w));
}
__device__ __forceinline__ float comp(const float4 v, const int kk) {
  return kk == 0 ? v.x : (kk == 1 ? v.y : (kk == 2 ? v.z : v.w));
}

__global__ __launch_bounds__(256, 2)
void covnet_mlp(const float* __restrict__ Pp,
                const float* __restrict__ W1, const float* __restrict__ B1,
                const float* __restrict__ W2, const float* __restrict__ B2,
                const float* __restrict__ W3, const float* __restrict__ B3,
                float* __restrict__ outg) {
  __shared__ float s_ld[TBA][DSTR];    // 4.6 KB
  __shared__ float s_h1[TBA][HSTR];    // 33.3 KB
  __shared__ float s_h2[TBA][HSTR];    // 33.3 KB -> 71 KB total, 2 blocks/CU
  const int tid = threadIdx.x;
  const int jt  = tid & 63;           // 64 column groups of 4
  const int b0  = (tid >> 6) * 8;     // 8 batch rows per thread
  const long base_b = (long)blockIdx.x * TBA;

  // ---- phase 0: log of clipped diagonal ----
  for (int idx = tid; idx < TBA * NXD; idx += 256) {
    const int b = idx >> 5, i = idx & 31;
    const float v = Pp[(base_b + b) * (NXD * NXD) + i * (NXD + 1)];
    s_ld[b][i] = __logf(fmaxf(v, 1e-6f));
  }
  __syncthreads();

  // ---- phase 1: h1 = tanh(ld @ W1 + b1), K=32, N=256 ----
  {
    float4 acc[8];
#pragma unroll
    for (int bb = 0; bb < 8; ++bb) acc[bb] = make_float4(0.f, 0.f, 0.f, 0.f);
#pragma unroll
    for (int k4 = 0; k4 < NXD / 4; ++k4) {
      float4 hA[8];
#pragma unroll
      for (int bb = 0; bb < 8; ++bb) hA[bb] = ld4(&s_ld[b0 + bb][4 * k4]);
#pragma unroll
      for (int kk = 0; kk < 4; ++kk) {
        const float4 w = ld4(W1 + (4 * k4 + kk) * HID + 4 * jt);
#pragma unroll
        for (int bb = 0; bb < 8; ++bb) fma4(acc[bb], comp(hA[bb], kk), w);
      }
    }
    const float4 bv = ld4(B1 + 4 * jt);
#pragma unroll
    for (int bb = 0; bb < 8; ++bb)
      *(float4*)&s_h1[b0 + bb][4 * jt] = ftanh4(acc[bb], bv);
  }
  __syncthreads();

  // ---- phase 2: h2 = tanh(h1 @ W2 + b2), K=256, N=256 ----
  {
    float4 acc[8];
#pragma unroll
    for (int bb = 0; bb < 8; ++bb) acc[bb] = make_float4(0.f, 0.f, 0.f, 0.f);
#pragma unroll 2
    for (int k4 = 0; k4 < HID / 4; ++k4) {
      float4 hA[8];
#pragma unroll
      for (int bb = 0; bb < 8; ++bb) hA[bb] = ld4(&s_h1[b0 + bb][4 * k4]);
#pragma unroll
      for (int kk = 0; kk < 4; ++kk) {
        const float4 w = ld4(W2 + (4 * k4 + kk) * HID + 4 * jt);
#pragma unroll
        for (int bb = 0; bb < 8; ++bb) fma4(acc[bb], comp(hA[bb], kk), w);
      }
    }
    const float4 bv = ld4(B2 + 4 * jt);
#pragma unroll
    for (int bb = 0; bb < 8; ++bb)
      *(float4*)&s_h2[b0 + bb][4 * jt] = ftanh4(acc[bb], bv);
  }
  __syncthreads();

  // ---- phase 3 main: out[:, 0:512] = h2 @ W3 + b3 ----
  {
    float4 acc[8][2];
#pragma unroll
    for (int bb = 0; bb < 8; ++bb) {
      acc[bb][0] = make_float4(0.f, 0.f, 0.f, 0.f);
      acc[bb][1] = make_float4(0.f, 0.f, 0.f, 0.f);
    }
#pragma unroll 2
    for (int k4 = 0; k4 < HID / 4; ++k4) {
      float4 hA[8];
#pragma unroll
      for (int bb = 0; bb < 8; ++bb) hA[bb] = ld4(&s_h2[b0 + bb][4 * k4]);
#pragma unroll
      for (int kk = 0; kk < 4; ++kk) {
        const float* wr = W3 + (4 * k4 + kk) * NOUTC + 4 * jt;
        const float4 w0 = ld4(wr);
        const float4 w1 = ld4(wr + 256);
#pragma unroll
        for (int bb = 0; bb < 8; ++bb) {
          const float h = comp(hA[bb], kk);
          fma4(acc[bb][0], h, w0);
          fma4(acc[bb][1], h, w1);
        }
      }
    }
    const float4 bv0 = ld4(B3 + 4 * jt);
    const float4 bv1 = ld4(B3 + 4 * jt + 256);
#pragma unroll
    for (int bb = 0; bb < 8; ++bb) {
      float4 r0 = acc[bb][0], r1 = acc[bb][1];
      r0.x += bv0.x; r0.y += bv0.y; r0.z += bv0.z; r0.w += bv0.w;
      r1.x += bv1.x; r1.y += bv1.y; r1.z += bv1.z; r1.w += bv1.w;
      float* ob = outg + (base_b + b0 + bb) * 1024;
      *(float4*)&ob[4 * jt]       = r0;
      *(float4*)&ob[4 * jt + 256] = r1;
    }
  }

  // ---- phase 3 tail: out[:, 512:528] ----
  {
    const int col = 512 + (tid & 15);
    const int bA  = tid >> 4;          // 0..15
    const int bB  = bA + 16;
    float a0 = 0.f, a1 = 0.f;
#pragma unroll 4
    for (int k = 0; k < HID; ++k) {
      const float w = W3[k * NOUTC + col];
      a0 = fmaf(s_h2[bA][k], w, a0);
      a1 = fmaf(s_h2[bB][k], w, a1);
    }
    const float bv = B3[col];
    outg[(base_b + bA) * 1024 + col] = a0 + bv;
    outg[(base_b + bB) * 1024 + col] = a1 + bv;
  }
}

__global__ __launch_bounds__(128, 2)
void covnet_llt(float* io, const float* __restrict__ Q) {
  __shared__ float s_L[TBB * SLAB];   // 36992 B -> 4 blocks/CU
  const int tid = threadIdx.x;
  const long base_b = (long)blockIdx.x * TBB;

  // ---- zero-init slabs (vector stores) ----
  {
    const float4 z = make_float4(0.f, 0.f, 0.f, 0.f);
    for (int q = tid; q < TBB * SLAB / 4; q += 128) ((float4*)s_L)[q] = z;
  }
  __syncthreads();

  // ---- lower-tri: enumerate tril index t -> coalesced 496-float runs ----
  for (int idx = tid; idx < TBB * NLOW; idx += 128) {
    const int b = idx / NLOW, t = idx - b * NLOW;
    // row from triangular index; exact at boundaries (odd perfect squares
    // are exact in fp32, off-boundary margin ~0.065 >> sqrt ulp)
    const int r = (int)((1.f + sqrtf((float)(8 * t + 1))) * 0.5f);
    const int c = t - ((r * (r - 1)) >> 1);
    const float x = io[(base_b + b) * 1024 + 32 + t];
    const float xc = fminf(fmaxf(x, -15.f), 15.f);
    const float e = __expf(2.f * xc);
    s_L[b * SLAB + r * LSTR + c] = 0.1f * __fdividef(e - 1.f, e + 1.f);
  }
  // ---- diag: softplus, 2 iters ----
  for (int idx = tid; idx < TBB * NXD; idx += 128) {
    const int b = idx >> 5, r = idx & 31;
    const float x = io[(base_b + b) * 1024 + r];
    const float sp = (x > 20.f) ? x : __logf(1.f + __expf(x));
    s_L[b * SLAB + r * LSTR + r] = fminf(fmaxf(sp + 0.01f, 0.01f), 100.f);
  }
  __syncthreads();

  // ---- P[i][k] = dot(L row i, L row k); thread owns rows il, il+16 ----
  const int b  = tid >> 4;   // 0..7
  const int il = tid & 15;
  const int i0 = il, i1 = il + 16;
  const float* Lb = &s_L[b * SLAB];

  float4 r0[8], r1[8];
#pragma unroll
  for (int c4 = 0; c4 < 8; ++c4) {
    r0[c4] = ld4(&Lb[i0 * LSTR + c4 * 4]);
    r1[c4] = ld4(&Lb[i1 * LSTR + c4 * 4]);
  }

  float* out0 = io + (base_b + b) * 1024 + i0 * NXD;
  float* out1 = io + (base_b + b) * 1024 + i1 * NXD;
  const float* q0 = Q + i0 * NXD;
  const float* q1 = Q + i1 * NXD;

#pragma unroll
  for (int kc = 0; kc < 4; ++kc) {
    float p0[8], p1[8];
#pragma unroll
    for (int kk = 0; kk < 8; ++kk) { p0[kk] = 0.f; p1[kk] = 0.f; }
#pragma unroll
    for (int kk = 0; kk < 8; ++kk) {
      const float* lk = &Lb[(kc * 8 + kk) * LSTR];   // row-k broadcast
#pragma unroll
      for (int c4 = 0; c4 < 8; ++c4) {
        const float4 w = ld4(&lk[c4 * 4]);
        p0[kk] = fmaf(r0[c4].x, w.x, p0[kk]);
        p0[kk] = fmaf(r0[c4].y, w.y, p0[kk]);
        p0[kk] = fmaf(r0[c4].z, w.z, p0[kk]);
        p0[kk] = fmaf(r0[c4].w, w.w, p0[kk]);
        p1[kk] = fmaf(r1[c4].x, w.x, p1[kk]);
        p1[kk] = fmaf(r1[c4].y, w.y, p1[kk]);
        p1[kk] = fmaf(r1[c4].z, w.z, p1[kk]);
        p1[kk] = fmaf(r1[c4].w, w.w, p1[kk]);
      }
    }
    const float4 qa0 = ld4(&q0[kc * 8]), qb0 = ld4(&q0[kc * 8 + 4]);
    const float4 qa1 = ld4(&q1[kc * 8]), qb1 = ld4(&q1[kc * 8 + 4]);
    *(float4*)&out0[kc * 8] =
        make_float4(p0[0] + qa0.x, p0[1] + qa0.y, p0[2] + qa0.z, p0[3] + qa0.w);
    *(float4*)&out0[kc * 8 + 4] =
        make_float4(p0[4] + qb0.x, p0[5] + qb0.y, p0[6] + qb0.z, p0[7] + qb0.w);
    *(float4*)&out1[kc * 8] =
        make_float4(p1[0] + qa1.x, p1[1] + qa1.y, p1[2] + qa1.z, p1[3] + qa1.w);
    *(float4*)&out1[kc * 8 + 4] =
        make_float4(p1[4] + qb1.x, p1[5] + qb1.y, p1[6] + qb1.z, p1[7] + qb1.w);
  }
}

extern "C" void kernel_launch(void* const* d_in, const int* in_sizes, int n_in,
                              void* d_out, int out_size, void* d_ws, size_t ws_size,
                              hipStream_t stream) {
  (void)n_in; (void)out_size; (void)d_ws; (void)ws_size;
  const float* Pp = (const float*)d_in[0];
  const float* W1 = (const float*)d_in[1];
  const float* B1 = (const float*)d_in[2];
  const float* W2 = (const float*)d_in[3];
  const float* B2 = (const float*)d_in[4];
  const float* W3 = (const float*)d_in[5];
  const float* B3 = (const float*)d_in[6];
  const float* Q  = (const float*)d_in[7];
  float* out = (float*)d_out;
  const int nb = in_sizes[0] / (NXD * NXD);   // 65536
  covnet_mlp<<<dim3(nb / TBA), dim3(256), 0, stream>>>(Pp, W1, B1, W2, B2, W3, B3, out);
  covnet_llt<<<dim3(nb / TBB), dim3(128), 0, stream>>>(out, Q);
}